// Round 1
// baseline (209.750 us; speedup 1.0000x reference)
//
#include <hip/hip_runtime.h>

// Dice loss (hard, exclude background=class 0), B=2, C=8, S=128^3.
// pred: (B, C, 128,128,128) fp32 ; ref: (B, 1, 128,128,128) int32 ; out: scalar fp32.

#define S_VOX (128 * 128 * 128)   // 2,097,152 voxels per (b, c) slice
#define S4    (S_VOX / 4)         // 524,288 float4 groups per slice
#define NC    8                   // channels
#define NFG   7                   // foreground classes (1..7)

// ws layout (int): per batch b: [b*21 + 0..6]=inter, [7..13]=psum(pred), [14..20]=rsum(ref)
#define WS_INTS (2 * 3 * NFG)

// Per-component argmax + predicated counter update. All indices compile-time
// after unroll -> counters stay in VGPRs (no scratch, no dynamic indexing).
#define PROC_COMP(C)                                                     \
    {                                                                    \
        float bv = a0.C; int bi = 0;                                     \
        if (a1.C > bv) { bv = a1.C; bi = 1; }                            \
        if (a2.C > bv) { bv = a2.C; bi = 2; }                            \
        if (a3.C > bv) { bv = a3.C; bi = 3; }                            \
        if (a4.C > bv) { bv = a4.C; bi = 4; }                            \
        if (a5.C > bv) { bv = a5.C; bi = 5; }                            \
        if (a6.C > bv) { bv = a6.C; bi = 6; }                            \
        if (a7.C > bv) { bv = a7.C; bi = 7; }                            \
        const int rr = r.C;                                              \
        _Pragma("unroll")                                                \
        for (int c = 1; c < NC; ++c) {                                   \
            cp[c - 1] += (bi == c);                                      \
            cr[c - 1] += (rr == c);                                      \
            ci[c - 1] += (int)((bi == c) & (rr == c));                   \
        }                                                                \
    }

__global__ __launch_bounds__(256) void dice_count_kernel(
    const float4* __restrict__ pred4, const int4* __restrict__ ref4,
    int* __restrict__ ws)
{
    const int b = blockIdx.y;
    int ci[NFG], cp[NFG], cr[NFG];
#pragma unroll
    for (int k = 0; k < NFG; ++k) { ci[k] = 0; cp[k] = 0; cr[k] = 0; }

    const int tid      = blockIdx.x * blockDim.x + threadIdx.x;
    const int nthreads = gridDim.x * blockDim.x;
    // base offsets in float4 / int4 units
    const long long predBase = (long long)b * NC * S4;
    const long long refBase  = (long long)b * S4;

    for (int g = tid; g < S4; g += nthreads) {
        const float4 a0 = pred4[predBase + (long long)0 * S4 + g];
        const float4 a1 = pred4[predBase + (long long)1 * S4 + g];
        const float4 a2 = pred4[predBase + (long long)2 * S4 + g];
        const float4 a3 = pred4[predBase + (long long)3 * S4 + g];
        const float4 a4 = pred4[predBase + (long long)4 * S4 + g];
        const float4 a5 = pred4[predBase + (long long)5 * S4 + g];
        const float4 a6 = pred4[predBase + (long long)6 * S4 + g];
        const float4 a7 = pred4[predBase + (long long)7 * S4 + g];
        const int4   r  = ref4[refBase + g];
        PROC_COMP(x)
        PROC_COMP(y)
        PROC_COMP(z)
        PROC_COMP(w)
    }

    // Wave (64-lane) shuffle reduction of the 21 counters.
#pragma unroll
    for (int k = 0; k < NFG; ++k) {
#pragma unroll
        for (int off = 32; off > 0; off >>= 1) {
            ci[k] += __shfl_down(ci[k], off, 64);
            cp[k] += __shfl_down(cp[k], off, 64);
            cr[k] += __shfl_down(cr[k], off, 64);
        }
    }

    __shared__ int sh[3 * NFG];
    if (threadIdx.x < 3 * NFG) sh[threadIdx.x] = 0;
    __syncthreads();

    const int lane = threadIdx.x & 63;
    if (lane == 0) {
#pragma unroll
        for (int k = 0; k < NFG; ++k) {
            atomicAdd(&sh[k], ci[k]);
            atomicAdd(&sh[NFG + k], cp[k]);
            atomicAdd(&sh[2 * NFG + k], cr[k]);
        }
    }
    __syncthreads();

    if (threadIdx.x < 3 * NFG) {
        atomicAdd(&ws[b * (3 * NFG) + threadIdx.x], sh[threadIdx.x]);
    }
}

__global__ void dice_finalize_kernel(const int* __restrict__ ws,
                                     float* __restrict__ out)
{
    if (blockIdx.x == 0 && threadIdx.x == 0) {
        float total = 0.0f;
#pragma unroll
        for (int b = 0; b < 2; ++b) {
            const int* w = ws + b * (3 * NFG);
            float sumd = 0.0f, sumw = 0.0f;
#pragma unroll
            for (int k = 0; k < NFG; ++k) {
                const int I = w[k];
                const int P = w[NFG + k];
                const int R = w[2 * NFG + k];
                if (R > 0) {
                    sumw += 1.0f;
                    sumd += 2.0f * (float)I / (float)(P + R);
                }
            }
            total += sumd / sumw;   // matches reference (NaN if no ref classes)
        }
        out[0] = 0.5f * total;
    }
}

extern "C" void kernel_launch(void* const* d_in, const int* in_sizes, int n_in,
                              void* d_out, int out_size, void* d_ws, size_t ws_size,
                              hipStream_t stream) {
    const float* pred = (const float*)d_in[0];
    const int*   ref  = (const int*)d_in[1];
    float*       out  = (float*)d_out;
    int*         ws   = (int*)d_ws;

    // ws is re-poisoned to 0xAA before every timed launch -> zero it each call.
    hipMemsetAsync(ws, 0, WS_INTS * sizeof(int), stream);

    // 512 blocks (2/CU, 8 waves/CU) x 256 threads; grid.y = batch.
    dim3 grid(256, 2, 1);
    dim3 block(256, 1, 1);
    dice_count_kernel<<<grid, block, 0, stream>>>(
        (const float4*)pred, (const int4*)ref, ws);
    dice_finalize_kernel<<<1, 64, 0, stream>>>(ws, out);
}